// Round 1
// baseline (174.851 us; speedup 1.0000x reference)
//
#include <hip/hip_runtime.h>

#define N_CLASSES 91
#define NBINS (3 * N_CLASSES)
// padded per-wave histogram stride to spread banks a bit
#define HPAD (N_CLASSES + 1)

__global__ void miou_zero_ws(unsigned int* __restrict__ ws) {
    int i = threadIdx.x + blockIdx.x * blockDim.x;
    if (i < NBINS) ws[i] = 0u;
}

__global__ __launch_bounds__(256) void miou_hist(const float* __restrict__ inp,
                                                 const int* __restrict__ tgt,
                                                 unsigned int* __restrict__ ws,
                                                 int n4) {
    // 4 waves per block, each wave gets its own 3 histograms
    __shared__ unsigned int h[4][3][HPAD];
    const int wave = threadIdx.x >> 6;

    for (int i = threadIdx.x; i < 4 * 3 * HPAD; i += blockDim.x)
        ((unsigned int*)h)[i] = 0u;
    __syncthreads();

    const int stride = gridDim.x * blockDim.x;
    for (int idx = blockIdx.x * blockDim.x + threadIdx.x; idx < n4; idx += stride) {
        const float4 f = reinterpret_cast<const float4*>(inp)[idx];
        const int4  t = reinterpret_cast<const int4*>(tgt)[idx];
        const int x0 = (int)f.x, x1 = (int)f.y, x2 = (int)f.z, x3 = (int)f.w;

        atomicAdd(&h[wave][0][x0], 1u);
        atomicAdd(&h[wave][0][x1], 1u);
        atomicAdd(&h[wave][0][x2], 1u);
        atomicAdd(&h[wave][0][x3], 1u);

        atomicAdd(&h[wave][1][t.x], 1u);
        atomicAdd(&h[wave][1][t.y], 1u);
        atomicAdd(&h[wave][1][t.z], 1u);
        atomicAdd(&h[wave][1][t.w], 1u);

        if (x0 == t.x) atomicAdd(&h[wave][2][x0], 1u);
        if (x1 == t.y) atomicAdd(&h[wave][2][x1], 1u);
        if (x2 == t.z) atomicAdd(&h[wave][2][x2], 1u);
        if (x3 == t.w) atomicAdd(&h[wave][2][x3], 1u);
    }
    __syncthreads();

    // flush: one atomic per (hist, class) per block
    for (int i = threadIdx.x; i < NBINS; i += blockDim.x) {
        const int arr = i / N_CLASSES;
        const int c   = i - arr * N_CLASSES;
        const unsigned int s = h[0][arr][c] + h[1][arr][c] + h[2][arr][c] + h[3][arr][c];
        if (s) atomicAdd(&ws[i], s);
    }
}

__global__ __launch_bounds__(128) void miou_finalize(const unsigned int* __restrict__ ws,
                                                     const int* __restrict__ smooth,
                                                     float* __restrict__ out) {
    const int c = threadIdx.x;
    float s = 0.f, cnt = 0.f;
    if (c < N_CLASSES) {
        const float a     = (float)ws[c];
        const float b     = (float)ws[N_CLASSES + c];
        const float inter = (float)ws[2 * N_CLASSES + c];
        const float uni   = a + b - inter;
        if (uni != 0.f) {
            const float sm = (float)(*smooth);
            s   = (inter + sm) / (uni + sm);
            cnt = 1.f;
        }
    }
    // wave64 butterfly reduce
    #pragma unroll
    for (int off = 32; off > 0; off >>= 1) {
        s   += __shfl_down(s, off, 64);
        cnt += __shfl_down(cnt, off, 64);
    }
    __shared__ float ssum[2], scnt[2];
    const int wave = threadIdx.x >> 6;
    const int lane = threadIdx.x & 63;
    if (lane == 0) { ssum[wave] = s; scnt[wave] = cnt; }
    __syncthreads();
    if (threadIdx.x == 0) {
        const float tot = ssum[0] + ssum[1];
        const float n   = scnt[0] + scnt[1];
        out[0] = tot / n;
    }
}

extern "C" void kernel_launch(void* const* d_in, const int* in_sizes, int n_in,
                              void* d_out, int out_size, void* d_ws, size_t ws_size,
                              hipStream_t stream) {
    const float* inp   = (const float*)d_in[0];
    const int*   tgt   = (const int*)d_in[1];
    const int*   smooth = (const int*)d_in[2];
    float* out = (float*)d_out;
    unsigned int* ws = (unsigned int*)d_ws;

    const int n  = in_sizes[0];      // 16,777,216
    const int n4 = n >> 2;           // 4,194,304 vec4 items

    miou_zero_ws<<<1, 512, 0, stream>>>(ws);

    const int block = 256;
    int grid = (n4 + block - 1) / block;
    if (grid > 2048) grid = 2048;    // 8 blocks/CU, grid-stride the rest
    miou_hist<<<grid, block, 0, stream>>>(inp, tgt, ws, n4);

    miou_finalize<<<1, 128, 0, stream>>>(ws, smooth, out);
}